// Round 20
// baseline (263.874 us; speedup 1.0000x reference)
//
#include <hip/hip_runtime.h>
#include <hip/hip_bf16.h>
#include <math.h>

#define L_SEQ   2048
#define M_ROWS  4096            // B*L
#define DPROJ   4384
#define DPROJP  4480            // zx row stride (alignment)
#define NPROJ   4352            // in_proj computed cols: z(2048)+xBC(2304), 34*128
#define DINNER  2048
#define CONVDIM 2304
#define NST     128
#define NH      32
#define CHUNK   128             // SSD chunk length
#define NCH     16              // L_SEQ / CHUNK
#define CTR     32              // conv rows per tile
#define NTILE   (L_SEQ / CTR)   // 64
#define LOG2E   1.4426950408889634f

typedef __attribute__((ext_vector_type(8))) short short8;
typedef __attribute__((ext_vector_type(4))) float f32x4;
typedef unsigned short u16;

static __device__ __forceinline__ u16 bf16bits(float v) {
    __hip_bfloat16 t = __float2bfloat16(v);
    return *(u16*)&t;
}
static __device__ __forceinline__ float bits2f(u16 u) {
    return __uint_as_float((unsigned)u << 16);
}
// element index into a [rows][128] bf16 LDS buffer with 16B-slot XOR swizzle
static __device__ __forceinline__ int sidx(int row, int s) {
    return (row << 7) + ((((s >> 3) ^ (row & 7)) << 3) | (s & 7));
}
static __device__ __forceinline__ int sslot(int row, int ks) {  // ks = 16B slot 0..15
    return (row << 7) + ((ks ^ (row & 7)) << 3);
}
// async 16B global->LDS (wave-uniform LDS base + lane*16; source pre-swizzled)
static __device__ __forceinline__ void gload16(const void* g, void* l) {
    __builtin_amdgcn_global_load_lds(
        (const __attribute__((address_space(1))) void*)g,
        (__attribute__((address_space(3))) void*)l, 16, 0, 0);
}

// ---------------------------------------------------------------------------
// f32 -> bf16 conversion pre-passes
// ---------------------------------------------------------------------------
__global__ __launch_bounds__(256) void cvt_x_kernel(
    const float* __restrict__ x, u16* __restrict__ xbf)
{
    const int i = (blockIdx.x * 256 + threadIdx.x) * 4;
    const float4 v = *(const float4*)(x + i);
    xbf[i + 0] = bf16bits(v.x);
    xbf[i + 1] = bf16bits(v.y);
    xbf[i + 2] = bf16bits(v.z);
    xbf[i + 3] = bf16bits(v.w);
}

// in_proj weights: only rows [0, NPROJ) are needed (dt rows recomputed exactly)
__global__ __launch_bounds__(256) void cvt_win_kernel(
    const float* __restrict__ w0, const float* __restrict__ w1,
    u16* __restrict__ dst)
{
    const int dir = blockIdx.y;
    const float* __restrict__ w = dir ? w1 : w0;
    u16* __restrict__ d = dst + (size_t)dir * NPROJ * 512;
    const int i = (blockIdx.x * 256 + threadIdx.x) * 4;   // over NPROJ*512
    const float4 v = *(const float4*)(w + i);
    d[i + 0] = bf16bits(v.x);
    d[i + 1] = bf16bits(v.y);
    d[i + 2] = bf16bits(v.z);
    d[i + 3] = bf16bits(v.w);
}

__global__ __launch_bounds__(256) void cvt_wout_kernel(
    const float* __restrict__ w0, const float* __restrict__ w1,
    u16* __restrict__ dst)
{
    const int dir = blockIdx.y;
    const float* __restrict__ w = dir ? w1 : w0;
    u16* __restrict__ d = dst + (size_t)dir * 512 * DINNER;
    const int i = (blockIdx.x * 256 + threadIdx.x) * 4;
    const float4 v = *(const float4*)(w + i);
    d[i + 0] = bf16bits(v.x);
    d[i + 1] = bf16bits(v.y);
    d[i + 2] = bf16bits(v.z);
    d[i + 3] = bf16bits(v.w);
}

// ---------------------------------------------------------------------------
// in_proj GEMM (128x128 tile, bf16 out) — single-buffer structure.
// global_load_lds staging, XCD block swizzle.
// ---------------------------------------------------------------------------
__global__ __launch_bounds__(256) void gemm_mfma_in(
    const u16* __restrict__ A0, int lda,
    const u16* __restrict__ Bw, long long b_dir_off,
    u16* __restrict__ Cb, long long c_dir_off, int ldc,
    int K)
{
    const int dir = blockIdx.z;
    const int nwg  = gridDim.x * gridDim.y;
    const int flat = blockIdx.y * gridDim.x + blockIdx.x;
    const int q = nwg >> 3, r = nwg & 7;
    const int xcd = flat & 7, idx = flat >> 3;
    const int wg = (xcd < r) ? xcd * (q + 1) + idx
                             : r * (q + 1) + (xcd - r) * q + idx;
    const int m0 = (wg / gridDim.x) * 128;
    const int n0 = (wg % gridDim.x) * 128;

    const u16* __restrict__ A = A0;
    const u16* __restrict__ B = Bw + (size_t)dir * b_dir_off;

    __shared__ u16 Asl[128 * 64];
    __shared__ u16 Bsl[128 * 64];

    const int tid  = threadIdx.x;
    const int lane = tid & 63;
    const int wid  = tid >> 6;
    const int wr   = (wid >> 1) << 6;
    const int wc   = (wid & 1) << 6;
    const int l15  = lane & 15;
    const int l4   = lane >> 4;

    f32x4 acc[4][4];
#pragma unroll
    for (int m = 0; m < 4; ++m)
#pragma unroll
        for (int n = 0; n < 4; ++n) acc[m][n] = (f32x4)0.f;

    for (int k0 = 0; k0 < K; k0 += 64) {
        __syncthreads();
#pragma unroll
        for (int i = 0; i < 4; ++i) {
            const int c    = tid + (i << 8);
            const int row  = c >> 3;
            const int scol = ((c & 7) ^ (row & 7)) << 3;
            gload16(A + (size_t)(m0 + row) * lda + k0 + scol, (char*)Asl + (c << 4));
            gload16(B + (size_t)(n0 + row) * K   + k0 + scol, (char*)Bsl + (c << 4));
        }
        __syncthreads();

#pragma unroll
        for (int kh = 0; kh < 2; ++kh) {
            const int ks = (kh << 2) + l4;
            short8 a[4], b[4];
#pragma unroll
            for (int m = 0; m < 4; ++m) {
                const int R = wr + (m << 4) + l15;
                a[m] = *(const short8*)((const char*)Asl + (R << 7) + ((ks ^ (R & 7)) << 4));
            }
#pragma unroll
            for (int n = 0; n < 4; ++n) {
                const int R = wc + (n << 4) + l15;
                b[n] = *(const short8*)((const char*)Bsl + (R << 7) + ((ks ^ (R & 7)) << 4));
            }
#pragma unroll
            for (int m = 0; m < 4; ++m)
#pragma unroll
                for (int n = 0; n < 4; ++n)
                    acc[m][n] = __builtin_amdgcn_mfma_f32_16x16x32_bf16(
                        a[m], b[n], acc[m][n], 0, 0, 0);
        }
    }

#pragma unroll
    for (int m = 0; m < 4; ++m) {
        const int row0 = m0 + wr + (m << 4) + (l4 << 2);
#pragma unroll
        for (int n = 0; n < 4; ++n) {
            const int col = n0 + wc + (n << 4) + l15;
#pragma unroll
            for (int r2 = 0; r2 < 4; ++r2)
                Cb[(size_t)dir * c_dir_off + (size_t)(row0 + r2) * ldc + col] =
                    bf16bits(acc[m][n][r2]);
        }
    }
}

// ---------------------------------------------------------------------------
// out_proj GEMM: 128x64 tile — single-buffer structure.
// C[row][dir*512+col] = A @ B^T + x (residual). A = bf16 gated-y in zx.
// ---------------------------------------------------------------------------
__global__ __launch_bounds__(256) void gemm_out_kernel(
    const u16* __restrict__ Azx,           // zx base (y slice at +DINNER)
    const u16* __restrict__ Bw,            // w_out bf16, per-dir 512*2048
    const float* __restrict__ x,
    float* __restrict__ out)
{
    const int dir = blockIdx.z;
    const int nwg  = gridDim.x * gridDim.y;        // 8*32 = 256, %8==0
    const int flat = blockIdx.y * gridDim.x + blockIdx.x;
    const int q = nwg >> 3;
    const int xcd = flat & 7, idx = flat >> 3;
    const int wg = xcd * q + idx;
    const int m0 = (wg >> 3) * 128;                // n-fast within XCD chunk
    const int n0 = (wg & 7) * 64;

    const u16* __restrict__ A = Azx + (size_t)dir * M_ROWS * DPROJP + DINNER;
    const u16* __restrict__ B = Bw + (size_t)dir * 512 * DINNER;

    __shared__ u16 Asl[128 * 64];
    __shared__ u16 Bsl[64 * 64];

    const int tid  = threadIdx.x;
    const int lane = tid & 63;
    const int wid  = tid >> 6;
    const int wr   = (wid >> 1) << 6;      // 0 or 64  (m)
    const int wc   = (wid & 1) << 5;       // 0 or 32  (n)
    const int l15  = lane & 15;
    const int l4   = lane >> 4;

    f32x4 acc[4][2];
#pragma unroll
    for (int m = 0; m < 4; ++m)
#pragma unroll
        for (int n = 0; n < 2; ++n) acc[m][n] = (f32x4)0.f;

    for (int k0 = 0; k0 < DINNER; k0 += 64) {
        __syncthreads();
#pragma unroll
        for (int i = 0; i < 4; ++i) {
            const int c    = tid + (i << 8);       // 0..1023
            const int row  = c >> 3;
            const int scol = ((c & 7) ^ (row & 7)) << 3;
            gload16(A + (size_t)(m0 + row) * DPROJP + k0 + scol, (char*)Asl + (c << 4));
        }
#pragma unroll
        for (int i = 0; i < 2; ++i) {
            const int c    = tid + (i << 8);       // 0..511
            const int row  = c >> 3;
            const int scol = ((c & 7) ^ (row & 7)) << 3;
            gload16(B + (size_t)(n0 + row) * DINNER + k0 + scol, (char*)Bsl + (c << 4));
        }
        __syncthreads();

#pragma unroll
        for (int kh = 0; kh < 2; ++kh) {
            const int ks = (kh << 2) + l4;
            short8 a[4], b[2];
#pragma unroll
            for (int m = 0; m < 4; ++m) {
                const int R = wr + (m << 4) + l15;
                a[m] = *(const short8*)((const char*)Asl + (R << 7) + ((ks ^ (R & 7)) << 4));
            }
#pragma unroll
            for (int n = 0; n < 2; ++n) {
                const int R = wc + (n << 4) + l15;
                b[n] = *(const short8*)((const char*)Bsl + (R << 7) + ((ks ^ (R & 7)) << 4));
            }
#pragma unroll
            for (int m = 0; m < 4; ++m)
#pragma unroll
                for (int n = 0; n < 2; ++n)
                    acc[m][n] = __builtin_amdgcn_mfma_f32_16x16x32_bf16(
                        a[m], b[n], acc[m][n], 0, 0, 0);
        }
    }

#pragma unroll
    for (int m = 0; m < 4; ++m) {
        const int row0 = m0 + wr + (m << 4) + (l4 << 2);
#pragma unroll
        for (int n = 0; n < 2; ++n) {
            const int col = n0 + wc + (n << 4) + l15;
#pragma unroll
            for (int r2 = 0; r2 < 4; ++r2) {
                const float v = acc[m][n][r2] + x[(size_t)(row0 + r2) * 512 + col];
                out[(size_t)(row0 + r2) * 1024 + dir * 512 + col] = v;
            }
        }
    }
}

// ---------------------------------------------------------------------------
// Sliding-window depthwise conv(4) + SiLU over bf16 zx columns. CTR=32.
// ---------------------------------------------------------------------------
__global__ __launch_bounds__(256) void conv_kernel(
    const u16* __restrict__ zx,
    const float* __restrict__ cw0, const float* __restrict__ cw1,
    const float* __restrict__ cb0, const float* __restrict__ cb1,
    u16* __restrict__ xs, u16* __restrict__ Bbf, u16* __restrict__ Cbf)
{
    const int dir = blockIdx.z;
    const int c   = blockIdx.x * 256 + threadIdx.x;     // channel 0..2303
    const int b   = blockIdx.y >> 6;
    const int r0  = (blockIdx.y & (NTILE - 1)) * CTR;

    const float* __restrict__ cw = dir ? cw1 : cw0;
    const float w0 = cw[c * 4 + 0], w1 = cw[c * 4 + 1];
    const float w2 = cw[c * 4 + 2], w3 = cw[c * 4 + 3];
    const float bias = (dir ? cb1 : cb0)[c];

    const u16* __restrict__ zcol = zx + (size_t)dir * M_ROWS * DPROJP
        + (size_t)(b * L_SEQ) * DPROJP + DINNER + c;
    const size_t obase = (size_t)(dir * M_ROWS + b * L_SEQ);

    auto emit = [&](int l, float acc) {
        const float s = acc / (1.f + expf(-acc));
        const size_t orow = obase + l;
        if (c < DINNER)            xs[orow * DINNER + c] = bf16bits(s);
        else if (c < DINNER + NST) Bbf[orow * NST + (c - DINNER)] = bf16bits(s);
        else                       Cbf[orow * NST + (c - DINNER - NST)] = bf16bits(s);
    };

    if (dir == 0) {
        float h0 = (r0 - 3 >= 0) ? bits2f(zcol[(size_t)(r0 - 3) * DPROJP]) : 0.f;
        float h1 = (r0 - 2 >= 0) ? bits2f(zcol[(size_t)(r0 - 2) * DPROJP]) : 0.f;
        float h2 = (r0 - 1 >= 0) ? bits2f(zcol[(size_t)(r0 - 1) * DPROJP]) : 0.f;
#pragma unroll 8
        for (int l = r0; l < r0 + CTR; ++l) {
            const float zl = bits2f(zcol[(size_t)l * DPROJP]);
            float acc = bias;
            acc = fmaf(w0, h0, acc);
            acc = fmaf(w1, h1, acc);
            acc = fmaf(w2, h2, acc);
            acc = fmaf(w3, zl, acc);
            emit(l, acc);
            h0 = h1; h1 = h2; h2 = zl;
        }
    } else {
        const int le = r0 + CTR - 1;
        float h1 = (le + 1 < L_SEQ) ? bits2f(zcol[(size_t)(le + 1) * DPROJP]) : 0.f;
        float h2 = (le + 2 < L_SEQ) ? bits2f(zcol[(size_t)(le + 2) * DPROJP]) : 0.f;
        float h3 = (le + 3 < L_SEQ) ? bits2f(zcol[(size_t)(le + 3) * DPROJP]) : 0.f;
#pragma unroll 8
        for (int l = le; l >= r0; --l) {
            const float zl = bits2f(zcol[(size_t)l * DPROJP]);
            float acc = bias;
            acc = fmaf(w3, zl, acc);
            acc = fmaf(w2, h1, acc);
            acc = fmaf(w1, h2, acc);
            acc = fmaf(w0, h3, acc);
            emit(l, acc);
            h3 = h2; h2 = h1; h1 = zl;
        }
    }
}

// ---------------------------------------------------------------------------
// Exact-f32 dt as LDS-staged block GEMV. dta in BASE-2 log-decay.
// ---------------------------------------------------------------------------
__global__ __launch_bounds__(512) void dt_kernel(
    const float* __restrict__ x,
    const float* __restrict__ inw0, const float* __restrict__ inw1,
    const float* __restrict__ dtbias0, const float* __restrict__ dtbias1,
    const float* __restrict__ Alog0, const float* __restrict__ Alog1,
    float* __restrict__ dtb, float* __restrict__ dta)
{
    const int dir = blockIdx.y;
    const int r0  = blockIdx.x * 64;
    const int tid = threadIdx.x;

    __shared__ float wT[512 * 32];   // [k4][h][j], 64 KB
    __shared__ float sbias[NH], sa[NH];

    const float* __restrict__ w = (dir ? inw1 : inw0) + (size_t)(DINNER + CONVDIM) * 512;
    for (int i = tid; i < 4096; i += 512) {
        const int flat = i * 4;
        const int h = flat >> 9;
        const int k = flat & 511;
        const float4 v = *(const float4*)(w + flat);
        *(float4*)&wT[(k >> 2) * 128 + h * 4] = v;
    }
    if (tid < NH) {
        sbias[tid] = (dir ? dtbias1 : dtbias0)[tid];
        sa[tid] = -expf((dir ? Alog1 : Alog0)[tid]) * LOG2E;
    }
    __syncthreads();

    const int h  = tid & 31;
    const int rr = tid >> 5;
    const float bias = sbias[h];
    const float a = sa[h];

    for (int rp = 0; rp < 64; rp += 16) {
        const int row = r0 + rp + rr;
        const float4* __restrict__ xr = (const float4*)(x + (size_t)row * 512);
        float4 s4 = make_float4(0.f, 0.f, 0.f, 0.f);
#pragma unroll 8
        for (int k4 = 0; k4 < 128; ++k4) {
            const float4 xv = xr[k4];
            const float4 wv = *(const float4*)&wT[k4 * 128 + h * 4];
            s4.x = fmaf(xv.x, wv.x, s4.x);
            s4.y = fmaf(xv.y, wv.y, s4.y);
            s4.z = fmaf(xv.z, wv.z, s4.z);
            s4.w = fmaf(xv.w, wv.w, s4.w);
        }
        const float v = (s4.x + s4.y) + (s4.z + s4.w) + bias;
        const float sp = (v > 20.f) ? v : log1pf(expf(v));
        const size_t orow = (size_t)(dir * M_ROWS + row);
        dtb[orow * NH + h] = sp;
        dta[orow * NH + h] = sp * a;         // base-2 log-decay
    }
}

// ---------------------------------------------------------------------------
// S_raw = C @ B^T per (dir,b,chunk) — head-independent, computed once.
// ---------------------------------------------------------------------------
__global__ __launch_bounds__(256) void sraw_kernel(
    const u16* __restrict__ Bbf, const u16* __restrict__ Cbf,
    u16* __restrict__ Sraw)
{
    const int bx  = blockIdx.x;            // db*NCH + ch
    const int ch  = bx & (NCH - 1);
    const int db  = bx >> 4;               // dir*2+b
    const int dir = db >> 1, bb = db & 1;
    const int tid = threadIdx.x;
    const int wid = tid >> 6;
    const int lane = tid & 63;
    const int l15 = lane & 15, l4 = lane >> 4;
    const int t0  = ch * CHUNK;
    const size_t dbase = (size_t)(dir * M_ROWS + bb * L_SEQ);
    const size_t base  = ((size_t)bx) << 14;     // *128*128

    auto lidx = [&](int t) { return dir ? (L_SEQ - 1 - t) : t; };

    f32x4 accs[2][8];
#pragma unroll
    for (int m = 0; m < 2; ++m)
#pragma unroll
        for (int j = 0; j < 8; ++j) accs[m][j] = (f32x4)0.f;

    short8 af[2][4];
#pragma unroll
    for (int m = 0; m < 2; ++m) {
        const size_t crow = dbase + lidx(t0 + wid * 32 + m * 16 + l15);
#pragma unroll
        for (int kk = 0; kk < 4; ++kk)
            af[m][kk] = *(const short8*)(Cbf + crow * NST + kk * 32 + l4 * 8);
    }
#pragma unroll
    for (int j = 0; j < 8; ++j) {
        const size_t brow = dbase + lidx(t0 + j * 16 + l15);
        short8 bf_[4];
#pragma unroll
        for (int kk = 0; kk < 4; ++kk)
            bf_[kk] = *(const short8*)(Bbf + brow * NST + kk * 32 + l4 * 8);
#pragma unroll
        for (int m = 0; m < 2; ++m)
#pragma unroll
            for (int kk = 0; kk < 4; ++kk)
                accs[m][j] = __builtin_amdgcn_mfma_f32_16x16x32_bf16(
                    af[m][kk], bf_[kk], accs[m][j], 0, 0, 0);
    }

#pragma unroll
    for (int m = 0; m < 2; ++m)
#pragma unroll
        for (int j = 0; j < 8; ++j)
#pragma unroll
            for (int r = 0; r < 4; ++r) {
                const int t = wid * 32 + m * 16 + l4 * 4 + r;
                const int s = j * 16 + l15;
                Sraw[base + (size_t)t * 128 + s] = bf16bits(accs[m][j][r]);
            }
}

// ---------------------------------------------------------------------------
// SSD state pass, 512 threads / 8 waves: raw x/B prefetched into registers at
// kernel top (latency hidden under dt-load + prefix scan), full-width WBT
// built once, 2 barriers. state = X~T @ (r∘B)^T -> stateC.
// ---------------------------------------------------------------------------
__global__ __launch_bounds__(512) void ssd_state_kernel(
    const u16* __restrict__ xs, const u16* __restrict__ Bbf,
    const float* __restrict__ dtb, const float* __restrict__ dta,
    u16* __restrict__ stateC, float* __restrict__ betac)
{
    const int bx  = blockIdx.x;
    const int ch  = bx & (NCH - 1);
    const int bh  = bx >> 4;
    const int dir = bh >> 6;
    const int bb  = (bh >> 5) & 1;
    const int h   = bh & 31;
    const int tid = threadIdx.x;
    const int wid = tid >> 6;            // 0..7
    const int lane = tid & 63;
    const int l15 = lane & 15;
    const int l4  = lane >> 4;
    const int t0  = ch * CHUNK;
    const size_t dbase = (size_t)(dir * M_ROWS + bb * L_SEQ);

    __shared__ u16 XT[64 * 128];         // [p][s] 16 KB
    __shared__ u16 WBT[128 * 128];       // [n][s] 32 KB
    __shared__ float scum[CHUNK];
    __shared__ float sdt[CHUNK];

    auto lidx = [&](int t) { return dir ? (L_SEQ - 1 - t) : t; };

    // ---- top prefetch: raw x (16 elems) + raw B (32 elems) per thread ----
    const int sP = tid >> 2;             // 0..127 (shared s for both)
    const size_t grow = dbase + lidx(t0 + sP);
    const int p0 = (tid & 3) * 16;       // XT cols
    const int n0 = (tid & 3) * 32;       // WBT rows
    short8 xv[2], bv[4];
#pragma unroll
    for (int q = 0; q < 2; ++q)
        xv[q] = *(const short8*)(xs + grow * DINNER + h * 64 + p0 + q * 8);
#pragma unroll
    for (int q = 0; q < 4; ++q)
        bv[q] = *(const short8*)(Bbf + grow * NST + n0 + q * 8);

    // ---- phase A: dt loads + base-2 cumA prefix-sum (wave 0) ----
    if (tid >= 128 && tid < 256) {
        const int s = tid - 128;
        sdt[s] = dtb[(dbase + lidx(t0 + s)) * NH + h];
    }
    if (wid == 0) {
        float a0 = dta[(dbase + lidx(t0 + lane)) * NH + h];
        float a1 = dta[(dbase + lidx(t0 + 64 + lane)) * NH + h];
#pragma unroll
        for (int off = 1; off < 64; off <<= 1) {
            const float u0 = __shfl_up(a0, off);
            const float u1 = __shfl_up(a1, off);
            if (lane >= off) { a0 += u0; a1 += u1; }
        }
        a1 += __shfl(a0, 63);
        scum[lane] = a0; scum[64 + lane] = a1;
        betac[(size_t)bh * L_SEQ + t0 + lane] = a0;
        betac[(size_t)bh * L_SEQ + t0 + 64 + lane] = a1;
    }
    __syncthreads();

    // ---- build X~T and WBT from prefetched registers ----
    {
        const float dts = sdt[sP];
        const float rs  = exp2f(scum[CHUNK - 1] - scum[sP]);
#pragma unroll
        for (int q = 0; q < 2; ++q)
#pragma unroll
            for (int j = 0; j < 8; ++j)
                XT[sidx(p0 + q * 8 + j, sP)] = bf16bits(dts * bits2f((u16)xv[q][j]));
#pragma unroll
        for (int q = 0; q < 4; ++q)
#pragma unroll
            for (int j = 0; j < 8; ++j)
                WBT[sidx(n0 + q * 8 + j, sP)] = bf16bits(rs * bits2f((u16)bv[q][j]));
    }
    __syncthreads();

    // ---- state GEMM: wave owns p-rows [pw,pw+16), n cols [nh,nh+64) ----
    const int pw = (wid >> 1) << 4;      // 0,16,32,48
    const int nh = (wid & 1) << 6;       // 0 or 64
    const int prow = pw + l15;
    short8 xa[4];
#pragma unroll
    for (int kk = 0; kk < 4; ++kk)
        xa[kk] = *(const short8*)(XT + sslot(prow, kk * 4 + l4));
    const size_t sbase = ((size_t)bh * NCH + ch) * 8192;
#pragma unroll
    for (int jn = 0; jn < 4; ++jn) {
        const int nrow = nh + jn * 16 + l15;
        f32x4 acc = (f32x4)0.f;
#pragma unroll
        for (int kk = 0; kk < 4; ++kk) {
            const short8 wb = *(const short8*)(WBT + sslot(nrow, kk * 4 + l4));
            acc = __builtin_amdgcn_mfma_f32_16x16x32_bf16(xa[kk], wb, acc, 0, 0, 0);
        }
#pragma unroll
        for (int r = 0; r < 4; ++r)
            stateC[sbase + (size_t)(pw + l4 * 4 + r) * 128 + nh + jn * 16 + l15] =
                bf16bits(acc[r]);
    }
}

// ---------------------------------------------------------------------------
// Combine: sequential over NCH chunks per bh (in place on stateC).
// ---------------------------------------------------------------------------
__global__ __launch_bounds__(512) void combine_kernel(
    u16* __restrict__ stateC, const float* __restrict__ betac)
{
    const int bh  = blockIdx.x;
    const int tid = threadIdx.x;

    float hrun[16];
#pragma unroll
    for (int j = 0; j < 16; ++j) hrun[j] = 0.f;

    for (int s = 0; s < NCH; ++s) {
        const size_t off = ((size_t)bh * NCH + s) * 8192 + (size_t)tid * 16;
        float c[16];
#pragma unroll
        for (int j = 0; j < 16; ++j) c[j] = bits2f(stateC[off + j]);
#pragma unroll
        for (int j = 0; j < 16; ++j) stateC[off + j] = bf16bits(hrun[j]);
        const float alpha = exp2f(betac[(size_t)bh * L_SEQ + s * CHUNK + (CHUNK - 1)]);
#pragma unroll
        for (int j = 0; j < 16; ++j) hrun[j] = fmaf(alpha, hrun[j], c[j]);
    }
}

// ---------------------------------------------------------------------------
// SSD output pass: 512 threads / 8 waves, h_in staged once per block (HS),
// Sraw/C/epilogue-xs prefetched at top.
// Y = P~@X~^T + (2^cumA ∘ C)@h_in^T + D*x -> yb (bf16).
// ---------------------------------------------------------------------------
__global__ __launch_bounds__(512) void ssd_out_kernel(
    const u16* __restrict__ xs, const u16* __restrict__ Cbf,
    const u16* __restrict__ Sraw, const u16* __restrict__ stateC,
    const float* __restrict__ dtb, const float* __restrict__ betac,
    const float* __restrict__ D0, const float* __restrict__ D1,
    u16* __restrict__ yb)
{
    const int bx  = blockIdx.x;
    const int ch  = bx & (NCH - 1);
    const int bh  = bx >> 4;
    const int dir = bh >> 6;
    const int bb  = (bh >> 5) & 1;
    const int h   = bh & 31;
    const int tid = threadIdx.x;
    const int wid = tid >> 6;            // 0..7
    const int lane = tid & 63;
    const int l15 = lane & 15;
    const int l4  = lane >> 4;
    const int t0  = ch * CHUNK;
    const size_t dbase = (size_t)(dir * M_ROWS + bb * L_SEQ);
    const float Dv = (dir ? D1 : D0)[h];

    __shared__ u16 XT[64 * 128];
    __shared__ u16 HS[64 * 128];         // h_in state, staged once per block
    __shared__ float scum[CHUNK];
    __shared__ float sdt[CHUNK];

    auto lidx = [&](int t) { return dir ? (L_SEQ - 1 - t) : t; };

    const int trow = wid * 16 + l15;     // this wave's t-row (0..127)
    const size_t sbraw = ((size_t)(((bh >> 5) * NCH) + ch)) << 14;
    const size_t crow = dbase + lidx(t0 + trow);
    const size_t sbase = ((size_t)bh * NCH + ch) * 8192;

    // ---- top prefetch (all addresses LDS-independent) ----
    short8 sv[4], c8[4];
#pragma unroll
    for (int kk = 0; kk < 4; ++kk) {
        const int sb = kk * 32 + l4 * 8;
        sv[kk] = *(const short8*)(Sraw + sbraw + (size_t)trow * 128 + sb);
        c8[kk] = *(const short8*)(Cbf + crow * NST + sb);
    }
    u16 xsv[16];
#pragma unroll
    for (int jp = 0; jp < 4; ++jp)
#pragma unroll
        for (int r = 0; r < 4; ++r) {
            const int t = wid * 16 + l4 * 4 + r;
            xsv[jp * 4 + r] =
                xs[(dbase + lidx(t0 + t)) * DINNER + h * 64 + jp * 16 + l15];
        }

    // ---- stage HS (coalesced, once per block) + phase A ----
#pragma unroll
    for (int i = 0; i < 2; ++i) {
        const int c = tid + (i << 9);          // 0..1023 16B slots
        const int row = c >> 4;                // 0..63
        const int sl  = c & 15;
        *(short8*)(HS + sslot(row, sl)) =
            *(const short8*)(stateC + sbase + (size_t)row * 128 + sl * 8);
    }
    if (tid < 128) {
        scum[tid] = betac[(size_t)bh * L_SEQ + t0 + tid];
    } else if (tid < 256) {
        const int s = tid - 128;
        sdt[s] = dtb[(dbase + lidx(t0 + s)) * NH + h];
    }
    __syncthreads();

    // build X~T (512 threads: s = tid>>2, 16 p-elems each)
    {
        const int s = tid >> 2;
        const float dts = sdt[s];
        const size_t grow = dbase + lidx(t0 + s);
        const int p0 = (tid & 3) * 16;
        const u16* __restrict__ xp = xs + grow * DINNER + h * 64 + p0;
#pragma unroll
        for (int q = 0; q < 2; ++q) {
            short8 v = *(const short8*)(xp + q * 8);
#pragma unroll
            for (int j = 0; j < 8; ++j) {
                const int p = p0 + q * 8 + j;
                XT[sidx(p, s)] = bf16bits(dts * bits2f((u16)v[j]));
            }
        }
    }
    __syncthreads();

    u16* __restrict__ ybase = yb + (size_t)dir * M_ROWS * DINNER;

    // Γ-scale the prefetched fragments in-register
    const float ct = scum[trow];
    const float gs = exp2f(ct);
    short8 pa[4], ga[4];
#pragma unroll
    for (int kk = 0; kk < 4; ++kk) {
        const int sb = kk * 32 + l4 * 8;
        short8 o, og;
#pragma unroll
        for (int j = 0; j < 8; ++j) {
            const float g = ((sb + j) <= trow) ? exp2f(ct - scum[sb + j]) : 0.f;
            o[j]  = (short)bf16bits(bits2f((u16)sv[kk][j]) * g);
            og[j] = (short)bf16bits(bits2f((u16)c8[kk][j]) * gs);
        }
        pa[kk] = o;
        ga[kk] = og;
    }

#pragma unroll
    for (int jp = 0; jp < 4; ++jp) {
        const int prow = jp * 16 + l15;
        short8 xb[4], hb[4];
#pragma unroll
        for (int kk = 0; kk < 4; ++kk) {
            xb[kk] = *(const short8*)(XT + sslot(prow, kk * 4 + l4));
            hb[kk] = *(const short8*)(HS + sslot(prow, kk * 4 + l4));
        }
        f32x4 acc = (f32x4)0.f;
#pragma unroll
        for (int kk = 0; kk < 4; ++kk)
            acc = __builtin_amdgcn_mfma_f32_16x16x32_bf16(
                pa[kk], xb[kk], acc, 0, 0, 0);
#pragma unroll
        for (int kk = 0; kk < 4; ++kk)
            acc = __builtin_amdgcn_mfma_f32_16x16x32_bf16(
                ga[kk], hb[kk], acc, 0, 0, 0);
#pragma unroll
        for (int r = 0; r < 4; ++r) {
            const int t = wid * 16 + l4 * 4 + r;
            const int lg = lidx(t0 + t);
            const float xv = bits2f(xsv[jp * 4 + r]);
            ybase[(size_t)(bb * L_SEQ + lg) * DINNER + h * 64 + prow] =
                bf16bits(acc[r] + Dv * xv);
        }
    }
}

// ---------------------------------------------------------------------------
// gate + RMSNorm: reads bf16 z + bf16 y, writes bf16 into zx cols [2048,4096).
// ---------------------------------------------------------------------------
__global__ __launch_bounds__(256) void gatenorm_kernel(
    u16* __restrict__ zx, const u16* __restrict__ yb,
    const float* __restrict__ nw0, const float* __restrict__ nw1)
{
    const int dir = blockIdx.y;
    const int row = blockIdx.x;
    const float* __restrict__ nw = dir ? nw1 : nw0;
    u16* __restrict__ zrow = zx + (size_t)dir * M_ROWS * DPROJP + (size_t)row * DPROJP;
    const u16* __restrict__ yrow = yb + (size_t)dir * M_ROWS * DINNER + (size_t)row * DINNER;
    const int tid = threadIdx.x;
    const int c0 = tid * 8;

    const short8 zv = *(const short8*)(zrow + c0);
    const short8 yv8 = *(const short8*)(yrow + c0);

    float g[8];
#pragma unroll
    for (int j = 0; j < 8; ++j) {
        const float z = bits2f((u16)zv[j]);
        g[j] = bits2f((u16)yv8[j]) * (z / (1.f + expf(-z)));
    }

    float ss = 0.f;
#pragma unroll
    for (int j = 0; j < 8; ++j) ss = fmaf(g[j], g[j], ss);
#pragma unroll
    for (int off = 1; off < 64; off <<= 1) ss += __shfl_xor(ss, off);
    __shared__ float red[4];
    if ((tid & 63) == 0) red[tid >> 6] = ss;
    __syncthreads();
    const float total = red[0] + red[1] + red[2] + red[3];
    const float rs = rsqrtf(total * (1.f / (float)DINNER) + 1e-5f);

    const float4 w0 = *(const float4*)(nw + c0);
    const float4 w1 = *(const float4*)(nw + c0 + 4);
    const float wv[8] = {w0.x, w0.y, w0.z, w0.w, w1.x, w1.y, w1.z, w1.w};
    short8 outv;
#pragma unroll
    for (int j = 0; j < 8; ++j) outv[j] = (short)bf16bits(g[j] * rs * wv[j]);
    *(short8*)(zrow + DINNER + c0) = outv;
}

// ---------------------------------------------------------------------------
extern "C" void kernel_launch(void* const* d_in, const int* in_sizes, int n_in,
                              void* d_out, int out_size, void* d_ws, size_t ws_size,
                              hipStream_t stream)
{
    (void)in_sizes; (void)n_in; (void)out_size; (void)ws_size;
    const float* x        = (const float*)d_in[0];
    const float* f_in_w   = (const float*)d_in[1];
    const float* f_conv_w = (const float*)d_in[2];
    const float* f_conv_b = (const float*)d_in[3];
    const float* f_dtbias = (const float*)d_in[4];
    const float* f_Alog   = (const float*)d_in[5];
    const float* f_D      = (const float*)d_in[6];
    const float* f_nw     = (const float*)d_in[7];
    const float* f_out_w  = (const float*)d_in[8];
    const float* b_in_w   = (const float*)d_in[9];
    const float* b_conv_w = (const float*)d_in[10];
    const float* b_conv_b = (const float*)d_in[11];
    const float* b_dtbias = (const float*)d_in[12];
    const float* b_Alog   = (const float*)d_in[13];
    const float* b_D      = (const float*)d_in[14];
    const float* b_nw     = (const float*)d_in[15];
    const float* b_out_w  = (const float*)d_in[16];

    // Workspace (~201 MB)
    u16* zx  = (u16*)d_ws;
    u16* xs  = zx + (size_t)2 * M_ROWS * DPROJP;
    u16* Bbf = xs + (size_t)2 * M_ROWS * DINNER;
    u16* Cbf = Bbf + (size_t)2 * M_ROWS * NST;
    float* dtb = (float*)(Cbf + (size_t)2 * M_ROWS * NST);
    float* dta = dtb + (size_t)2 * M_ROWS * NH;
    u16* stateC = (u16*)(dta + (size_t)2 * M_ROWS * NH);
    float* betac = (float*)(stateC + (size_t)128 * NCH * 8192);
    u16* yb = (u16*)(betac + (size_t)128 * L_SEQ);
    u16* x_bf   = yb + (size_t)2 * M_ROWS * DINNER;
    u16* w_in_bf  = x_bf + (size_t)M_ROWS * 512;
    u16* w_out_bf = w_in_bf + (size_t)2 * DPROJP * 512;   // only 2*NPROJ*512 used
    u16* Sraw = w_out_bf + (size_t)2 * 512 * DINNER;

    // 0) dtype conversions
    cvt_x_kernel<<<dim3(M_ROWS * 512 / 1024), 256, 0, stream>>>(x, x_bf);
    cvt_win_kernel<<<dim3(NPROJ * 512 / 1024, 2), 256, 0, stream>>>(f_in_w, b_in_w, w_in_bf);
    cvt_wout_kernel<<<dim3(512 * DINNER / 1024, 2), 256, 0, stream>>>(f_out_w, b_out_w, w_out_bf);

    // 1) in_proj (MFMA, bf16 out): zx = x @ in_w^T  (N trimmed to 4352)
    gemm_mfma_in<<<dim3(NPROJ / 128, M_ROWS / 128, 2), 256, 0, stream>>>(
        x_bf, 512,
        w_in_bf, (long long)NPROJ * 512,
        zx, (long long)M_ROWS * DPROJP, DPROJP,
        512);

    // 2a) sliding-window conv + SiLU (bf16 in/out), CTR=32
    conv_kernel<<<dim3(CONVDIM / 256, 2 * NTILE, 2), 256, 0, stream>>>(
        zx, f_conv_w, b_conv_w, f_conv_b, b_conv_b, xs, Bbf, Cbf);

    // 2b) exact-f32 dt / base-2 log-decay (LDS-staged GEMV)
    dt_kernel<<<dim3(M_ROWS / 64, 2), 512, 0, stream>>>(
        x, f_in_w, b_in_w, f_dtbias, b_dtbias, f_Alog, b_Alog, dtb, dta);

    // 3a) head-independent S_raw = C @ B^T (once per dir,b,chunk)
    sraw_kernel<<<dim3(4 * NCH), 256, 0, stream>>>(Bbf, Cbf, Sraw);

    // 3b) state pass (cumA -> betac, chunk states -> stateC), 512-thread
    ssd_state_kernel<<<dim3(128 * NCH), 512, 0, stream>>>(
        xs, Bbf, dtb, dta, stateC, betac);

    // 3c) combine chunk states (stateC becomes h_in per chunk)
    combine_kernel<<<dim3(128), 512, 0, stream>>>(stateC, betac);

    // 3d) output pass: local Y + fused correction + D-skip -> yb (bf16)
    ssd_out_kernel<<<dim3(128 * NCH), 512, 0, stream>>>(
        xs, Cbf, Sraw, stateC, dtb, betac, f_D, b_D, yb);

    // 4) gate + RMSNorm: bf16 result into zx cols [2048,4096)
    gatenorm_kernel<<<dim3(M_ROWS, 2), 256, 0, stream>>>(zx, yb, f_nw, b_nw);

    // 5) out_proj (128x64 tiles) + residual + concat
    gemm_out_kernel<<<dim3(8, 32, 2), 256, 0, stream>>>(
        zx, w_out_bf, x, (float*)d_out);
}

// Round 21
// 260.336 us; speedup vs baseline: 1.0136x; 1.0136x over previous
//
#include <hip/hip_runtime.h>
#include <hip/hip_bf16.h>
#include <math.h>

#define L_SEQ   2048
#define M_ROWS  4096            // B*L
#define DPROJ   4384
#define DPROJP  4480            // zx row stride (alignment)
#define NPROJ   4352            // in_proj computed cols: z(2048)+xBC(2304), 34*128
#define DINNER  2048
#define CONVDIM 2304
#define NST     128
#define NH      32
#define CHUNK   128             // SSD chunk length
#define NCH     16              // L_SEQ / CHUNK
#define CTR     32              // conv rows per tile
#define NTILE   (L_SEQ / CTR)   // 64
#define LOG2E   1.4426950408889634f

typedef __attribute__((ext_vector_type(8))) short short8;
typedef __attribute__((ext_vector_type(4))) float f32x4;
typedef unsigned short u16;

static __device__ __forceinline__ u16 bf16bits(float v) {
    __hip_bfloat16 t = __float2bfloat16(v);
    return *(u16*)&t;
}
static __device__ __forceinline__ float bits2f(u16 u) {
    return __uint_as_float((unsigned)u << 16);
}
// element index into a [rows][128] bf16 LDS buffer with 16B-slot XOR swizzle
static __device__ __forceinline__ int sidx(int row, int s) {
    return (row << 7) + ((((s >> 3) ^ (row & 7)) << 3) | (s & 7));
}
static __device__ __forceinline__ int sslot(int row, int ks) {  // ks = 16B slot 0..15
    return (row << 7) + ((ks ^ (row & 7)) << 3);
}
// async 16B global->LDS (wave-uniform LDS base + lane*16; source pre-swizzled)
static __device__ __forceinline__ void gload16(const void* g, void* l) {
    __builtin_amdgcn_global_load_lds(
        (const __attribute__((address_space(1))) void*)g,
        (__attribute__((address_space(3))) void*)l, 16, 0, 0);
}

// ---------------------------------------------------------------------------
// f32 -> bf16 conversion pre-passes
// ---------------------------------------------------------------------------
__global__ __launch_bounds__(256) void cvt_x_kernel(
    const float* __restrict__ x, u16* __restrict__ xbf)
{
    const int i = (blockIdx.x * 256 + threadIdx.x) * 4;
    const float4 v = *(const float4*)(x + i);
    xbf[i + 0] = bf16bits(v.x);
    xbf[i + 1] = bf16bits(v.y);
    xbf[i + 2] = bf16bits(v.z);
    xbf[i + 3] = bf16bits(v.w);
}

// in_proj weights: only rows [0, NPROJ) are needed (dt rows recomputed exactly)
__global__ __launch_bounds__(256) void cvt_win_kernel(
    const float* __restrict__ w0, const float* __restrict__ w1,
    u16* __restrict__ dst)
{
    const int dir = blockIdx.y;
    const float* __restrict__ w = dir ? w1 : w0;
    u16* __restrict__ d = dst + (size_t)dir * NPROJ * 512;
    const int i = (blockIdx.x * 256 + threadIdx.x) * 4;   // over NPROJ*512
    const float4 v = *(const float4*)(w + i);
    d[i + 0] = bf16bits(v.x);
    d[i + 1] = bf16bits(v.y);
    d[i + 2] = bf16bits(v.z);
    d[i + 3] = bf16bits(v.w);
}

// out_proj weights with norm_w folded in: w'[o][k] = w[o][k] * nw[k]
__global__ __launch_bounds__(256) void cvt_wout_kernel(
    const float* __restrict__ w0, const float* __restrict__ w1,
    const float* __restrict__ nw0, const float* __restrict__ nw1,
    u16* __restrict__ dst)
{
    const int dir = blockIdx.y;
    const float* __restrict__ w = dir ? w1 : w0;
    const float* __restrict__ nw = dir ? nw1 : nw0;
    u16* __restrict__ d = dst + (size_t)dir * 512 * DINNER;
    const int i = (blockIdx.x * 256 + threadIdx.x) * 4;
    const int k = i & (DINNER - 1);
    const float4 v = *(const float4*)(w + i);
    d[i + 0] = bf16bits(v.x * nw[k + 0]);
    d[i + 1] = bf16bits(v.y * nw[k + 1]);
    d[i + 2] = bf16bits(v.z * nw[k + 2]);
    d[i + 3] = bf16bits(v.w * nw[k + 3]);
}

// ---------------------------------------------------------------------------
// in_proj GEMM (128x128 tile, bf16 out) — single-buffer structure.
// ---------------------------------------------------------------------------
__global__ __launch_bounds__(256) void gemm_mfma_in(
    const u16* __restrict__ A0, int lda,
    const u16* __restrict__ Bw, long long b_dir_off,
    u16* __restrict__ Cb, long long c_dir_off, int ldc,
    int K)
{
    const int dir = blockIdx.z;
    const int nwg  = gridDim.x * gridDim.y;
    const int flat = blockIdx.y * gridDim.x + blockIdx.x;
    const int q = nwg >> 3, r = nwg & 7;
    const int xcd = flat & 7, idx = flat >> 3;
    const int wg = (xcd < r) ? xcd * (q + 1) + idx
                             : r * (q + 1) + (xcd - r) * q + idx;
    const int m0 = (wg / gridDim.x) * 128;
    const int n0 = (wg % gridDim.x) * 128;

    const u16* __restrict__ A = A0;
    const u16* __restrict__ B = Bw + (size_t)dir * b_dir_off;

    __shared__ u16 Asl[128 * 64];
    __shared__ u16 Bsl[128 * 64];

    const int tid  = threadIdx.x;
    const int lane = tid & 63;
    const int wid  = tid >> 6;
    const int wr   = (wid >> 1) << 6;
    const int wc   = (wid & 1) << 6;
    const int l15  = lane & 15;
    const int l4   = lane >> 4;

    f32x4 acc[4][4];
#pragma unroll
    for (int m = 0; m < 4; ++m)
#pragma unroll
        for (int n = 0; n < 4; ++n) acc[m][n] = (f32x4)0.f;

    for (int k0 = 0; k0 < K; k0 += 64) {
        __syncthreads();
#pragma unroll
        for (int i = 0; i < 4; ++i) {
            const int c    = tid + (i << 8);
            const int row  = c >> 3;
            const int scol = ((c & 7) ^ (row & 7)) << 3;
            gload16(A + (size_t)(m0 + row) * lda + k0 + scol, (char*)Asl + (c << 4));
            gload16(B + (size_t)(n0 + row) * K   + k0 + scol, (char*)Bsl + (c << 4));
        }
        __syncthreads();

#pragma unroll
        for (int kh = 0; kh < 2; ++kh) {
            const int ks = (kh << 2) + l4;
            short8 a[4], b[4];
#pragma unroll
            for (int m = 0; m < 4; ++m) {
                const int R = wr + (m << 4) + l15;
                a[m] = *(const short8*)((const char*)Asl + (R << 7) + ((ks ^ (R & 7)) << 4));
            }
#pragma unroll
            for (int n = 0; n < 4; ++n) {
                const int R = wc + (n << 4) + l15;
                b[n] = *(const short8*)((const char*)Bsl + (R << 7) + ((ks ^ (R & 7)) << 4));
            }
#pragma unroll
            for (int m = 0; m < 4; ++m)
#pragma unroll
                for (int n = 0; n < 4; ++n)
                    acc[m][n] = __builtin_amdgcn_mfma_f32_16x16x32_bf16(
                        a[m], b[n], acc[m][n], 0, 0, 0);
        }
    }

#pragma unroll
    for (int m = 0; m < 4; ++m) {
        const int row0 = m0 + wr + (m << 4) + (l4 << 2);
#pragma unroll
        for (int n = 0; n < 4; ++n) {
            const int col = n0 + wc + (n << 4) + l15;
#pragma unroll
            for (int r2 = 0; r2 < 4; ++r2)
                Cb[(size_t)dir * c_dir_off + (size_t)(row0 + r2) * ldc + col] =
                    bf16bits(acc[m][n][r2]);
        }
    }
}

// ---------------------------------------------------------------------------
// out_proj GEMM: 128x64 tile, A = gated y (yb, compact), epilogue scales by
// per-row rs (RMSNorm factored out) and adds residual x.
// ---------------------------------------------------------------------------
__global__ __launch_bounds__(256) void gemm_out_kernel(
    const u16* __restrict__ Ag,            // yb: [2*M][DINNER] bf16 gated y
    const u16* __restrict__ Bw,            // w_out*nw bf16, per-dir 512*2048
    const float* __restrict__ rs,          // [2*M] per-row rsqrt factors
    const float* __restrict__ x,
    float* __restrict__ out)
{
    const int dir = blockIdx.z;
    const int nwg  = gridDim.x * gridDim.y;        // 8*32 = 256, %8==0
    const int flat = blockIdx.y * gridDim.x + blockIdx.x;
    const int q = nwg >> 3;
    const int xcd = flat & 7, idx = flat >> 3;
    const int wg = xcd * q + idx;
    const int m0 = (wg >> 3) * 128;                // n-fast within XCD chunk
    const int n0 = (wg & 7) * 64;

    const u16* __restrict__ A = Ag + (size_t)dir * M_ROWS * DINNER;
    const u16* __restrict__ B = Bw + (size_t)dir * 512 * DINNER;
    const float* __restrict__ rsd = rs + (size_t)dir * M_ROWS;

    __shared__ u16 Asl[128 * 64];
    __shared__ u16 Bsl[64 * 64];

    const int tid  = threadIdx.x;
    const int lane = tid & 63;
    const int wid  = tid >> 6;
    const int wr   = (wid >> 1) << 6;      // 0 or 64  (m)
    const int wc   = (wid & 1) << 5;       // 0 or 32  (n)
    const int l15  = lane & 15;
    const int l4   = lane >> 4;

    f32x4 acc[4][2];
#pragma unroll
    for (int m = 0; m < 4; ++m)
#pragma unroll
        for (int n = 0; n < 2; ++n) acc[m][n] = (f32x4)0.f;

    for (int k0 = 0; k0 < DINNER; k0 += 64) {
        __syncthreads();
#pragma unroll
        for (int i = 0; i < 4; ++i) {
            const int c    = tid + (i << 8);       // 0..1023
            const int row  = c >> 3;
            const int scol = ((c & 7) ^ (row & 7)) << 3;
            gload16(A + (size_t)(m0 + row) * DINNER + k0 + scol, (char*)Asl + (c << 4));
        }
#pragma unroll
        for (int i = 0; i < 2; ++i) {
            const int c    = tid + (i << 8);       // 0..511
            const int row  = c >> 3;
            const int scol = ((c & 7) ^ (row & 7)) << 3;
            gload16(B + (size_t)(n0 + row) * DINNER + k0 + scol, (char*)Bsl + (c << 4));
        }
        __syncthreads();

#pragma unroll
        for (int kh = 0; kh < 2; ++kh) {
            const int ks = (kh << 2) + l4;
            short8 a[4], b[2];
#pragma unroll
            for (int m = 0; m < 4; ++m) {
                const int R = wr + (m << 4) + l15;
                a[m] = *(const short8*)((const char*)Asl + (R << 7) + ((ks ^ (R & 7)) << 4));
            }
#pragma unroll
            for (int n = 0; n < 2; ++n) {
                const int R = wc + (n << 4) + l15;
                b[n] = *(const short8*)((const char*)Bsl + (R << 7) + ((ks ^ (R & 7)) << 4));
            }
#pragma unroll
            for (int m = 0; m < 4; ++m)
#pragma unroll
                for (int n = 0; n < 2; ++n)
                    acc[m][n] = __builtin_amdgcn_mfma_f32_16x16x32_bf16(
                        a[m], b[n], acc[m][n], 0, 0, 0);
        }
    }

#pragma unroll
    for (int m = 0; m < 4; ++m) {
        const int row0 = m0 + wr + (m << 4) + (l4 << 2);
#pragma unroll
        for (int n = 0; n < 2; ++n) {
            const int col = n0 + wc + (n << 4) + l15;
#pragma unroll
            for (int r2 = 0; r2 < 4; ++r2) {
                const float v = acc[m][n][r2] * rsd[row0 + r2]
                              + x[(size_t)(row0 + r2) * 512 + col];
                out[(size_t)(row0 + r2) * 1024 + dir * 512 + col] = v;
            }
        }
    }
}

// ---------------------------------------------------------------------------
// Sliding-window depthwise conv(4) + SiLU over bf16 zx columns. CTR=32.
// ---------------------------------------------------------------------------
__global__ __launch_bounds__(256) void conv_kernel(
    const u16* __restrict__ zx,
    const float* __restrict__ cw0, const float* __restrict__ cw1,
    const float* __restrict__ cb0, const float* __restrict__ cb1,
    u16* __restrict__ xs, u16* __restrict__ Bbf, u16* __restrict__ Cbf)
{
    const int dir = blockIdx.z;
    const int c   = blockIdx.x * 256 + threadIdx.x;     // channel 0..2303
    const int b   = blockIdx.y >> 6;
    const int r0  = (blockIdx.y & (NTILE - 1)) * CTR;

    const float* __restrict__ cw = dir ? cw1 : cw0;
    const float w0 = cw[c * 4 + 0], w1 = cw[c * 4 + 1];
    const float w2 = cw[c * 4 + 2], w3 = cw[c * 4 + 3];
    const float bias = (dir ? cb1 : cb0)[c];

    const u16* __restrict__ zcol = zx + (size_t)dir * M_ROWS * DPROJP
        + (size_t)(b * L_SEQ) * DPROJP + DINNER + c;
    const size_t obase = (size_t)(dir * M_ROWS + b * L_SEQ);

    auto emit = [&](int l, float acc) {
        const float s = acc / (1.f + expf(-acc));
        const size_t orow = obase + l;
        if (c < DINNER)            xs[orow * DINNER + c] = bf16bits(s);
        else if (c < DINNER + NST) Bbf[orow * NST + (c - DINNER)] = bf16bits(s);
        else                       Cbf[orow * NST + (c - DINNER - NST)] = bf16bits(s);
    };

    if (dir == 0) {
        float h0 = (r0 - 3 >= 0) ? bits2f(zcol[(size_t)(r0 - 3) * DPROJP]) : 0.f;
        float h1 = (r0 - 2 >= 0) ? bits2f(zcol[(size_t)(r0 - 2) * DPROJP]) : 0.f;
        float h2 = (r0 - 1 >= 0) ? bits2f(zcol[(size_t)(r0 - 1) * DPROJP]) : 0.f;
#pragma unroll 8
        for (int l = r0; l < r0 + CTR; ++l) {
            const float zl = bits2f(zcol[(size_t)l * DPROJP]);
            float acc = bias;
            acc = fmaf(w0, h0, acc);
            acc = fmaf(w1, h1, acc);
            acc = fmaf(w2, h2, acc);
            acc = fmaf(w3, zl, acc);
            emit(l, acc);
            h0 = h1; h1 = h2; h2 = zl;
        }
    } else {
        const int le = r0 + CTR - 1;
        float h1 = (le + 1 < L_SEQ) ? bits2f(zcol[(size_t)(le + 1) * DPROJP]) : 0.f;
        float h2 = (le + 2 < L_SEQ) ? bits2f(zcol[(size_t)(le + 2) * DPROJP]) : 0.f;
        float h3 = (le + 3 < L_SEQ) ? bits2f(zcol[(size_t)(le + 3) * DPROJP]) : 0.f;
#pragma unroll 8
        for (int l = le; l >= r0; --l) {
            const float zl = bits2f(zcol[(size_t)l * DPROJP]);
            float acc = bias;
            acc = fmaf(w3, zl, acc);
            acc = fmaf(w2, h1, acc);
            acc = fmaf(w1, h2, acc);
            acc = fmaf(w0, h3, acc);
            emit(l, acc);
            h3 = h2; h2 = h1; h1 = zl;
        }
    }
}

// ---------------------------------------------------------------------------
// Exact-f32 dt as LDS-staged block GEMV. dta in BASE-2 log-decay.
// ---------------------------------------------------------------------------
__global__ __launch_bounds__(512) void dt_kernel(
    const float* __restrict__ x,
    const float* __restrict__ inw0, const float* __restrict__ inw1,
    const float* __restrict__ dtbias0, const float* __restrict__ dtbias1,
    const float* __restrict__ Alog0, const float* __restrict__ Alog1,
    float* __restrict__ dtb, float* __restrict__ dta)
{
    const int dir = blockIdx.y;
    const int r0  = blockIdx.x * 64;
    const int tid = threadIdx.x;

    __shared__ float wT[512 * 32];   // [k4][h][j], 64 KB
    __shared__ float sbias[NH], sa[NH];

    const float* __restrict__ w = (dir ? inw1 : inw0) + (size_t)(DINNER + CONVDIM) * 512;
    for (int i = tid; i < 4096; i += 512) {
        const int flat = i * 4;
        const int h = flat >> 9;
        const int k = flat & 511;
        const float4 v = *(const float4*)(w + flat);
        *(float4*)&wT[(k >> 2) * 128 + h * 4] = v;
    }
    if (tid < NH) {
        sbias[tid] = (dir ? dtbias1 : dtbias0)[tid];
        sa[tid] = -expf((dir ? Alog1 : Alog0)[tid]) * LOG2E;
    }
    __syncthreads();

    const int h  = tid & 31;
    const int rr = tid >> 5;
    const float bias = sbias[h];
    const float a = sa[h];

    for (int rp = 0; rp < 64; rp += 16) {
        const int row = r0 + rp + rr;
        const float4* __restrict__ xr = (const float4*)(x + (size_t)row * 512);
        float4 s4 = make_float4(0.f, 0.f, 0.f, 0.f);
#pragma unroll 8
        for (int k4 = 0; k4 < 128; ++k4) {
            const float4 xv = xr[k4];
            const float4 wv = *(const float4*)&wT[k4 * 128 + h * 4];
            s4.x = fmaf(xv.x, wv.x, s4.x);
            s4.y = fmaf(xv.y, wv.y, s4.y);
            s4.z = fmaf(xv.z, wv.z, s4.z);
            s4.w = fmaf(xv.w, wv.w, s4.w);
        }
        const float v = (s4.x + s4.y) + (s4.z + s4.w) + bias;
        const float sp = (v > 20.f) ? v : log1pf(expf(v));
        const size_t orow = (size_t)(dir * M_ROWS + row);
        dtb[orow * NH + h] = sp;
        dta[orow * NH + h] = sp * a;         // base-2 log-decay
    }
}

// ---------------------------------------------------------------------------
// S_raw = C @ B^T per (dir,b,chunk) — head-independent, computed once.
// ---------------------------------------------------------------------------
__global__ __launch_bounds__(256) void sraw_kernel(
    const u16* __restrict__ Bbf, const u16* __restrict__ Cbf,
    u16* __restrict__ Sraw)
{
    const int bx  = blockIdx.x;            // db*NCH + ch
    const int ch  = bx & (NCH - 1);
    const int db  = bx >> 4;               // dir*2+b
    const int dir = db >> 1, bb = db & 1;
    const int tid = threadIdx.x;
    const int wid = tid >> 6;
    const int lane = tid & 63;
    const int l15 = lane & 15, l4 = lane >> 4;
    const int t0  = ch * CHUNK;
    const size_t dbase = (size_t)(dir * M_ROWS + bb * L_SEQ);
    const size_t base  = ((size_t)bx) << 14;     // *128*128

    auto lidx = [&](int t) { return dir ? (L_SEQ - 1 - t) : t; };

    f32x4 accs[2][8];
#pragma unroll
    for (int m = 0; m < 2; ++m)
#pragma unroll
        for (int j = 0; j < 8; ++j) accs[m][j] = (f32x4)0.f;

    short8 af[2][4];
#pragma unroll
    for (int m = 0; m < 2; ++m) {
        const size_t crow = dbase + lidx(t0 + wid * 32 + m * 16 + l15);
#pragma unroll
        for (int kk = 0; kk < 4; ++kk)
            af[m][kk] = *(const short8*)(Cbf + crow * NST + kk * 32 + l4 * 8);
    }
#pragma unroll
    for (int j = 0; j < 8; ++j) {
        const size_t brow = dbase + lidx(t0 + j * 16 + l15);
        short8 bf_[4];
#pragma unroll
        for (int kk = 0; kk < 4; ++kk)
            bf_[kk] = *(const short8*)(Bbf + brow * NST + kk * 32 + l4 * 8);
#pragma unroll
        for (int m = 0; m < 2; ++m)
#pragma unroll
            for (int kk = 0; kk < 4; ++kk)
                accs[m][j] = __builtin_amdgcn_mfma_f32_16x16x32_bf16(
                    af[m][kk], bf_[kk], accs[m][j], 0, 0, 0);
    }

#pragma unroll
    for (int m = 0; m < 2; ++m)
#pragma unroll
        for (int j = 0; j < 8; ++j)
#pragma unroll
            for (int r = 0; r < 4; ++r) {
                const int t = wid * 32 + m * 16 + l4 * 4 + r;
                const int s = j * 16 + l15;
                Sraw[base + (size_t)t * 128 + s] = bf16bits(accs[m][j][r]);
            }
}

// ---------------------------------------------------------------------------
// SSD state pass, 512 threads / 8 waves: raw x/B prefetched into registers at
// kernel top, full-width WBT built once, 2 barriers.
// ---------------------------------------------------------------------------
__global__ __launch_bounds__(512) void ssd_state_kernel(
    const u16* __restrict__ xs, const u16* __restrict__ Bbf,
    const float* __restrict__ dtb, const float* __restrict__ dta,
    u16* __restrict__ stateC, float* __restrict__ betac)
{
    const int bx  = blockIdx.x;
    const int ch  = bx & (NCH - 1);
    const int bh  = bx >> 4;
    const int dir = bh >> 6;
    const int bb  = (bh >> 5) & 1;
    const int h   = bh & 31;
    const int tid = threadIdx.x;
    const int wid = tid >> 6;            // 0..7
    const int lane = tid & 63;
    const int l15 = lane & 15;
    const int l4  = lane >> 4;
    const int t0  = ch * CHUNK;
    const size_t dbase = (size_t)(dir * M_ROWS + bb * L_SEQ);

    __shared__ u16 XT[64 * 128];         // [p][s] 16 KB
    __shared__ u16 WBT[128 * 128];       // [n][s] 32 KB
    __shared__ float scum[CHUNK];
    __shared__ float sdt[CHUNK];

    auto lidx = [&](int t) { return dir ? (L_SEQ - 1 - t) : t; };

    // ---- top prefetch: raw x (16 elems) + raw B (32 elems) per thread ----
    const int sP = tid >> 2;             // 0..127 (shared s for both)
    const size_t grow = dbase + lidx(t0 + sP);
    const int p0 = (tid & 3) * 16;       // XT cols
    const int n0 = (tid & 3) * 32;       // WBT rows
    short8 xv[2], bv[4];
#pragma unroll
    for (int q = 0; q < 2; ++q)
        xv[q] = *(const short8*)(xs + grow * DINNER + h * 64 + p0 + q * 8);
#pragma unroll
    for (int q = 0; q < 4; ++q)
        bv[q] = *(const short8*)(Bbf + grow * NST + n0 + q * 8);

    // ---- phase A: dt loads + base-2 cumA prefix-sum (wave 0) ----
    if (tid >= 128 && tid < 256) {
        const int s = tid - 128;
        sdt[s] = dtb[(dbase + lidx(t0 + s)) * NH + h];
    }
    if (wid == 0) {
        float a0 = dta[(dbase + lidx(t0 + lane)) * NH + h];
        float a1 = dta[(dbase + lidx(t0 + 64 + lane)) * NH + h];
#pragma unroll
        for (int off = 1; off < 64; off <<= 1) {
            const float u0 = __shfl_up(a0, off);
            const float u1 = __shfl_up(a1, off);
            if (lane >= off) { a0 += u0; a1 += u1; }
        }
        a1 += __shfl(a0, 63);
        scum[lane] = a0; scum[64 + lane] = a1;
        betac[(size_t)bh * L_SEQ + t0 + lane] = a0;
        betac[(size_t)bh * L_SEQ + t0 + 64 + lane] = a1;
    }
    __syncthreads();

    // ---- build X~T and WBT from prefetched registers ----
    {
        const float dts = sdt[sP];
        const float rs  = exp2f(scum[CHUNK - 1] - scum[sP]);
#pragma unroll
        for (int q = 0; q < 2; ++q)
#pragma unroll
            for (int j = 0; j < 8; ++j)
                XT[sidx(p0 + q * 8 + j, sP)] = bf16bits(dts * bits2f((u16)xv[q][j]));
#pragma unroll
        for (int q = 0; q < 4; ++q)
#pragma unroll
            for (int j = 0; j < 8; ++j)
                WBT[sidx(n0 + q * 8 + j, sP)] = bf16bits(rs * bits2f((u16)bv[q][j]));
    }
    __syncthreads();

    // ---- state GEMM: wave owns p-rows [pw,pw+16), n cols [nh,nh+64) ----
    const int pw = (wid >> 1) << 4;      // 0,16,32,48
    const int nh = (wid & 1) << 6;       // 0 or 64
    const int prow = pw + l15;
    short8 xa[4];
#pragma unroll
    for (int kk = 0; kk < 4; ++kk)
        xa[kk] = *(const short8*)(XT + sslot(prow, kk * 4 + l4));
    const size_t sbase = ((size_t)bh * NCH + ch) * 8192;
#pragma unroll
    for (int jn = 0; jn < 4; ++jn) {
        const int nrow = nh + jn * 16 + l15;
        f32x4 acc = (f32x4)0.f;
#pragma unroll
        for (int kk = 0; kk < 4; ++kk) {
            const short8 wb = *(const short8*)(WBT + sslot(nrow, kk * 4 + l4));
            acc = __builtin_amdgcn_mfma_f32_16x16x32_bf16(xa[kk], wb, acc, 0, 0, 0);
        }
#pragma unroll
        for (int r = 0; r < 4; ++r)
            stateC[sbase + (size_t)(pw + l4 * 4 + r) * 128 + nh + jn * 16 + l15] =
                bf16bits(acc[r]);
    }
}

// ---------------------------------------------------------------------------
// Combine: sequential over NCH chunks per bh (in place on stateC).
// ---------------------------------------------------------------------------
__global__ __launch_bounds__(512) void combine_kernel(
    u16* __restrict__ stateC, const float* __restrict__ betac)
{
    const int bh  = blockIdx.x;
    const int tid = threadIdx.x;

    float hrun[16];
#pragma unroll
    for (int j = 0; j < 16; ++j) hrun[j] = 0.f;

    for (int s = 0; s < NCH; ++s) {
        const size_t off = ((size_t)bh * NCH + s) * 8192 + (size_t)tid * 16;
        float c[16];
#pragma unroll
        for (int j = 0; j < 16; ++j) c[j] = bits2f(stateC[off + j]);
#pragma unroll
        for (int j = 0; j < 16; ++j) stateC[off + j] = bf16bits(hrun[j]);
        const float alpha = exp2f(betac[(size_t)bh * L_SEQ + s * CHUNK + (CHUNK - 1)]);
#pragma unroll
        for (int j = 0; j < 16; ++j) hrun[j] = fmaf(alpha, hrun[j], c[j]);
    }
}

// ---------------------------------------------------------------------------
// SSD output pass + FUSED GATE: 512 threads / 8 waves, h_in staged once (HS),
// Sraw/C/xs/z prefetched at top. Writes g = (Y + D*x) * silu(z) -> yb (bf16).
// ---------------------------------------------------------------------------
__global__ __launch_bounds__(512) void ssd_out_kernel(
    const u16* __restrict__ xs, const u16* __restrict__ Cbf,
    const u16* __restrict__ Sraw, const u16* __restrict__ stateC,
    const u16* __restrict__ zx,
    const float* __restrict__ dtb, const float* __restrict__ betac,
    const float* __restrict__ D0, const float* __restrict__ D1,
    u16* __restrict__ yb)
{
    const int bx  = blockIdx.x;
    const int ch  = bx & (NCH - 1);
    const int bh  = bx >> 4;
    const int dir = bh >> 6;
    const int bb  = (bh >> 5) & 1;
    const int h   = bh & 31;
    const int tid = threadIdx.x;
    const int wid = tid >> 6;            // 0..7
    const int lane = tid & 63;
    const int l15 = lane & 15;
    const int l4  = lane >> 4;
    const int t0  = ch * CHUNK;
    const size_t dbase = (size_t)(dir * M_ROWS + bb * L_SEQ);
    const float Dv = (dir ? D1 : D0)[h];

    __shared__ u16 XT[64 * 128];
    __shared__ u16 HS[64 * 128];         // h_in state, staged once per block
    __shared__ float scum[CHUNK];
    __shared__ float sdt[CHUNK];

    auto lidx = [&](int t) { return dir ? (L_SEQ - 1 - t) : t; };

    const int trow = wid * 16 + l15;     // this wave's t-row (0..127)
    const size_t sbraw = ((size_t)(((bh >> 5) * NCH) + ch)) << 14;
    const size_t crow = dbase + lidx(t0 + trow);
    const size_t sbase = ((size_t)bh * NCH + ch) * 8192;

    // ---- top prefetch (all addresses LDS-independent) ----
    short8 sv[4], c8[4];
#pragma unroll
    for (int kk = 0; kk < 4; ++kk) {
        const int sb = kk * 32 + l4 * 8;
        sv[kk] = *(const short8*)(Sraw + sbraw + (size_t)trow * 128 + sb);
        c8[kk] = *(const short8*)(Cbf + crow * NST + sb);
    }
    u16 xsv[16], zsv[16];
#pragma unroll
    for (int jp = 0; jp < 4; ++jp)
#pragma unroll
        for (int r = 0; r < 4; ++r) {
            const int t = wid * 16 + l4 * 4 + r;
            const size_t gr = dbase + lidx(t0 + t);
            xsv[jp * 4 + r] = xs[gr * DINNER + h * 64 + jp * 16 + l15];
            zsv[jp * 4 + r] = zx[gr * DPROJP + h * 64 + jp * 16 + l15];
        }

    // ---- stage HS (coalesced, once per block) + phase A ----
#pragma unroll
    for (int i = 0; i < 2; ++i) {
        const int c = tid + (i << 9);          // 0..1023 16B slots
        const int row = c >> 4;                // 0..63
        const int sl  = c & 15;
        *(short8*)(HS + sslot(row, sl)) =
            *(const short8*)(stateC + sbase + (size_t)row * 128 + sl * 8);
    }
    if (tid < 128) {
        scum[tid] = betac[(size_t)bh * L_SEQ + t0 + tid];
    } else if (tid < 256) {
        const int s = tid - 128;
        sdt[s] = dtb[(dbase + lidx(t0 + s)) * NH + h];
    }
    __syncthreads();

    // build X~T (512 threads: s = tid>>2, 16 p-elems each)
    {
        const int s = tid >> 2;
        const float dts = sdt[s];
        const size_t grow = dbase + lidx(t0 + s);
        const int p0 = (tid & 3) * 16;
        const u16* __restrict__ xp = xs + grow * DINNER + h * 64 + p0;
#pragma unroll
        for (int q = 0; q < 2; ++q) {
            short8 v = *(const short8*)(xp + q * 8);
#pragma unroll
            for (int j = 0; j < 8; ++j) {
                const int p = p0 + q * 8 + j;
                XT[sidx(p, s)] = bf16bits(dts * bits2f((u16)v[j]));
            }
        }
    }
    __syncthreads();

    u16* __restrict__ ybase = yb + (size_t)dir * M_ROWS * DINNER;

    // Γ-scale the prefetched fragments in-register
    const float ct = scum[trow];
    const float gs = exp2f(ct);
    short8 pa[4], ga[4];
#pragma unroll
    for (int kk = 0; kk < 4; ++kk) {
        const int sb = kk * 32 + l4 * 8;
        short8 o, og;
#pragma unroll
        for (int j = 0; j < 8; ++j) {
            const float g = ((sb + j) <= trow) ? exp2f(ct - scum[sb + j]) : 0.f;
            o[j]  = (short)bf16bits(bits2f((u16)sv[kk][j]) * g);
            og[j] = (short)bf16bits(bits2f((u16)c8[kk][j]) * gs);
        }
        pa[kk] = o;
        ga[kk] = og;
    }

#pragma unroll
    for (int jp = 0; jp < 4; ++jp) {
        const int prow = jp * 16 + l15;
        short8 xb[4], hb[4];
#pragma unroll
        for (int kk = 0; kk < 4; ++kk) {
            xb[kk] = *(const short8*)(XT + sslot(prow, kk * 4 + l4));
            hb[kk] = *(const short8*)(HS + sslot(prow, kk * 4 + l4));
        }
        f32x4 acc = (f32x4)0.f;
#pragma unroll
        for (int kk = 0; kk < 4; ++kk)
            acc = __builtin_amdgcn_mfma_f32_16x16x32_bf16(
                pa[kk], xb[kk], acc, 0, 0, 0);
#pragma unroll
        for (int kk = 0; kk < 4; ++kk)
            acc = __builtin_amdgcn_mfma_f32_16x16x32_bf16(
                ga[kk], hb[kk], acc, 0, 0, 0);
#pragma unroll
        for (int r = 0; r < 4; ++r) {
            const int t = wid * 16 + l4 * 4 + r;
            const int lg = lidx(t0 + t);
            const float yv = acc[r] + Dv * bits2f(xsv[jp * 4 + r]);
            const float zz = bits2f(zsv[jp * 4 + r]);
            const float g  = yv * (zz / (1.f + expf(-zz)));
            ybase[(size_t)(bb * L_SEQ + lg) * DINNER + h * 64 + prow] = bf16bits(g);
        }
    }
}

// ---------------------------------------------------------------------------
// rs pass: per-row rsqrt(mean(g^2)+eps) over the gated y (yb). Read-only.
// ---------------------------------------------------------------------------
__global__ __launch_bounds__(256) void rs_kernel(
    const u16* __restrict__ yb, float* __restrict__ rs)
{
    const int dir = blockIdx.y;
    const int row = blockIdx.x;
    const u16* __restrict__ yrow = yb + ((size_t)dir * M_ROWS + row) * DINNER;
    const int tid = threadIdx.x;

    const short8 yv8 = *(const short8*)(yrow + tid * 8);
    float ss = 0.f;
#pragma unroll
    for (int j = 0; j < 8; ++j) {
        const float g = bits2f((u16)yv8[j]);
        ss = fmaf(g, g, ss);
    }
#pragma unroll
    for (int off = 1; off < 64; off <<= 1) ss += __shfl_xor(ss, off);
    __shared__ float red[4];
    if ((tid & 63) == 0) red[tid >> 6] = ss;
    __syncthreads();
    if (tid == 0) {
        const float total = red[0] + red[1] + red[2] + red[3];
        rs[(size_t)dir * M_ROWS + row] =
            rsqrtf(total * (1.f / (float)DINNER) + 1e-5f);
    }
}

// ---------------------------------------------------------------------------
extern "C" void kernel_launch(void* const* d_in, const int* in_sizes, int n_in,
                              void* d_out, int out_size, void* d_ws, size_t ws_size,
                              hipStream_t stream)
{
    (void)in_sizes; (void)n_in; (void)out_size; (void)ws_size;
    const float* x        = (const float*)d_in[0];
    const float* f_in_w   = (const float*)d_in[1];
    const float* f_conv_w = (const float*)d_in[2];
    const float* f_conv_b = (const float*)d_in[3];
    const float* f_dtbias = (const float*)d_in[4];
    const float* f_Alog   = (const float*)d_in[5];
    const float* f_D      = (const float*)d_in[6];
    const float* f_nw     = (const float*)d_in[7];
    const float* f_out_w  = (const float*)d_in[8];
    const float* b_in_w   = (const float*)d_in[9];
    const float* b_conv_w = (const float*)d_in[10];
    const float* b_conv_b = (const float*)d_in[11];
    const float* b_dtbias = (const float*)d_in[12];
    const float* b_Alog   = (const float*)d_in[13];
    const float* b_D      = (const float*)d_in[14];
    const float* b_nw     = (const float*)d_in[15];
    const float* b_out_w  = (const float*)d_in[16];

    // Workspace (~201 MB)
    u16* zx  = (u16*)d_ws;
    u16* xs  = zx + (size_t)2 * M_ROWS * DPROJP;
    u16* Bbf = xs + (size_t)2 * M_ROWS * DINNER;
    u16* Cbf = Bbf + (size_t)2 * M_ROWS * NST;
    float* dtb = (float*)(Cbf + (size_t)2 * M_ROWS * NST);
    float* dta = dtb + (size_t)2 * M_ROWS * NH;
    u16* stateC = (u16*)(dta + (size_t)2 * M_ROWS * NH);
    float* betac = (float*)(stateC + (size_t)128 * NCH * 8192);
    u16* yb = (u16*)(betac + (size_t)128 * L_SEQ);
    u16* x_bf   = yb + (size_t)2 * M_ROWS * DINNER;
    u16* w_in_bf  = x_bf + (size_t)M_ROWS * 512;
    u16* w_out_bf = w_in_bf + (size_t)2 * DPROJP * 512;   // only 2*NPROJ*512 used
    u16* Sraw = w_out_bf + (size_t)2 * 512 * DINNER;
    float* rsbuf = (float*)(Sraw + (size_t)64 * 128 * 128);   // 2*M floats

    // 0) dtype conversions (norm_w folded into out_proj weights)
    cvt_x_kernel<<<dim3(M_ROWS * 512 / 1024), 256, 0, stream>>>(x, x_bf);
    cvt_win_kernel<<<dim3(NPROJ * 512 / 1024, 2), 256, 0, stream>>>(f_in_w, b_in_w, w_in_bf);
    cvt_wout_kernel<<<dim3(512 * DINNER / 1024, 2), 256, 0, stream>>>(
        f_out_w, b_out_w, f_nw, b_nw, w_out_bf);

    // 1) in_proj (MFMA, bf16 out): zx = x @ in_w^T  (N trimmed to 4352)
    gemm_mfma_in<<<dim3(NPROJ / 128, M_ROWS / 128, 2), 256, 0, stream>>>(
        x_bf, 512,
        w_in_bf, (long long)NPROJ * 512,
        zx, (long long)M_ROWS * DPROJP, DPROJP,
        512);

    // 2a) sliding-window conv + SiLU (bf16 in/out), CTR=32
    conv_kernel<<<dim3(CONVDIM / 256, 2 * NTILE, 2), 256, 0, stream>>>(
        zx, f_conv_w, b_conv_w, f_conv_b, b_conv_b, xs, Bbf, Cbf);

    // 2b) exact-f32 dt / base-2 log-decay (LDS-staged GEMV)
    dt_kernel<<<dim3(M_ROWS / 64, 2), 512, 0, stream>>>(
        x, f_in_w, b_in_w, f_dtbias, b_dtbias, f_Alog, b_Alog, dtb, dta);

    // 3a) head-independent S_raw = C @ B^T (once per dir,b,chunk)
    sraw_kernel<<<dim3(4 * NCH), 256, 0, stream>>>(Bbf, Cbf, Sraw);

    // 3b) state pass (cumA -> betac, chunk states -> stateC)
    ssd_state_kernel<<<dim3(128 * NCH), 512, 0, stream>>>(
        xs, Bbf, dtb, dta, stateC, betac);

    // 3c) combine chunk states (stateC becomes h_in per chunk)
    combine_kernel<<<dim3(128), 512, 0, stream>>>(stateC, betac);

    // 3d) output pass + fused gate: g = (Y + D*x)*silu(z) -> yb (bf16)
    ssd_out_kernel<<<dim3(128 * NCH), 512, 0, stream>>>(
        xs, Cbf, Sraw, stateC, zx, dtb, betac, f_D, b_D, yb);

    // 4) per-row rsqrt factors (read-only pass over yb)
    rs_kernel<<<dim3(M_ROWS, 2), 256, 0, stream>>>(yb, rsbuf);

    // 5) out_proj on gated y, epilogue: acc * rs[row] + residual; concat
    gemm_out_kernel<<<dim3(8, 32, 2), 256, 0, stream>>>(
        yb, w_out_bf, rsbuf, x, (float*)d_out);
}